// Round 1
// baseline (1435.762 us; speedup 1.0000x reference)
//
#include <hip/hip_runtime.h>
#include <cstdint>
#include <cstddef>

#define BB 4
#define NN 4096
#define MM 4096
#define CC 64
#define KK 32

#define INF_F __builtin_huge_valf()

// ---------------------------------------------------------------------------
// Kernel T: transpose support_features [B,C,M] -> ft [B,M,C]
// ---------------------------------------------------------------------------
__global__ void pt_transpose_feat(const float* __restrict__ sf, float* __restrict__ ft) {
  int b = blockIdx.x >> 4;                         // 64 blocks = 4 b * 16
  int m = ((blockIdx.x & 15) << 8) + threadIdx.x;  // 256 m per block
  float v[CC];
#pragma unroll
  for (int c = 0; c < CC; ++c) v[c] = sf[((size_t)(b * CC + c)) * MM + m];
  float4* dst = (float4*)(ft + ((size_t)(b * MM + m)) * CC);
#pragma unroll
  for (int i = 0; i < CC / 4; ++i)
    dst[i] = make_float4(v[4 * i], v[4 * i + 1], v[4 * i + 2], v[4 * i + 3]);
}

// ---------------------------------------------------------------------------
// Kernel 1: exact top-32-nearest (masked) per query. One wave per query.
// Lanes 0..31 hold the current top-32 (unsorted); wave-wide consensus max.
// ---------------------------------------------------------------------------
__global__ void pt_knn_kernel(const float* __restrict__ qxyz, const float* __restrict__ sxyz,
                              const int* __restrict__ smask, int* __restrict__ oidx,
                              unsigned* __restrict__ ovalid, int* __restrict__ onn) {
  const int lane = threadIdx.x & 63;
  const int qi = blockIdx.x * 4 + (threadIdx.x >> 6);
  const int b = qi >> 12;           // /4096
  const float qx = qxyz[qi * 3 + 0];
  const float qy = qxyz[qi * 3 + 1];
  const float qz = qxyz[qi * 3 + 2];
  const float* sb = sxyz + (size_t)b * MM * 3;
  const int* mb = smask + (size_t)b * MM;

  float bd = INF_F;   // meaningful on lanes 0..31
  int bi = 0;
  float cmax = INF_F; // consensus max of top-32 (all lanes agree)
  int cml = 0;        // lane holding it

  for (int m0 = 0; m0 < MM; m0 += 64) {
    const int m = m0 + lane;
    const float sx = sb[m * 3 + 0];
    const float sy = sb[m * 3 + 1];
    const float sz = sb[m * 3 + 2];
    const float dx = sx - qx, dy = sy - qy, dz = sz - qz;
    float d = dx * dx + dy * dy + dz * dz;
    if (mb[m] <= 0) d = INF_F;

    unsigned long long cand = __ballot(d < cmax);
    while (cand) {
      const int src = __ffsll((unsigned long long)cand) - 1;
      cand &= cand - 1;
      const float dc = __shfl(d, src);
      if (dc < cmax) {                 // uniform branch (dc, cmax uniform)
        if (lane == cml) { bd = dc; bi = m0 + src; }
        // recompute consensus argmax of bd over lanes 0..31
        float v = (lane < 32) ? bd : -1.0f;
        int il = lane;
#pragma unroll
        for (int s = 0; s < 6; ++s) {
          const int mk = 1 << s;
          const float ov = __shfl_xor(v, mk);
          const int oi = __shfl_xor(il, mk);
          if (ov > v || (ov == v && oi < il)) { v = ov; il = oi; }
        }
        cmax = v; cml = il;
      }
    }
  }

  if (lane < 32) oidx[(size_t)qi * KK + lane] = bi;

  const float rr = (float)(0.1 * 0.1);
  unsigned long long vb = __ballot((lane < 32) && (bd <= rr));
  if (lane == 0) ovalid[qi] = (unsigned)(vb & 0xffffffffull);

  // nearest neighbor = min over the 32 (ties -> smaller index, matches argmin)
  float v = (lane < 32) ? bd : INF_F;
  int il = (lane < 32) ? bi : 0x7fffffff;
#pragma unroll
  for (int s = 0; s < 6; ++s) {
    const int mk = 1 << s;
    const float ov = __shfl_xor(v, mk);
    const int oi = __shfl_xor(il, mk);
    if (ov < v || (ov == v && oi < il)) { v = ov; il = oi; }
  }
  if (lane == 0) onn[qi] = il;
}

// ---------------------------------------------------------------------------
// Kernel 2: fully fused transform. Block = 256 threads = 4 waves = 8 queries.
// Wave = 2 queries; lane = (q = lane>>5, k = lane&31) -> one neighbor column.
// Activations live in registers per lane; W rows are wave-uniform loads.
// BUF columns are strictly per-lane (no cross-lane LDS traffic after sync).
// ---------------------------------------------------------------------------
__launch_bounds__(256, 2)
__global__ void pt_fused_kernel(
    const float* __restrict__ qxyz, const float* __restrict__ sxyz,
    const int* __restrict__ qmask, const float* __restrict__ ft,
    const int* __restrict__ kidx, const unsigned* __restrict__ kvalid,
    const int* __restrict__ knn_nn,
    const float* __restrict__ W1, const float* __restrict__ b1,
    const float* __restrict__ W2, const float* __restrict__ b2,
    const float* __restrict__ Wphi, const float* __restrict__ bphi,
    const float* __restrict__ Wpsi, const float* __restrict__ bpsi,
    const float* __restrict__ Wa, const float* __restrict__ ba,
    const float* __restrict__ Wg1, const float* __restrict__ bg1,
    const float* __restrict__ Wg2, const float* __restrict__ bg2,
    const float* __restrict__ gT, const float* __restrict__ beT,
    const float* __restrict__ rmT, const float* __restrict__ rvT,
    const float* __restrict__ gG, const float* __restrict__ beG,
    const float* __restrict__ rmG, const float* __restrict__ rvG,
    float* __restrict__ out) {
  __shared__ float BUF[4][CC][64];   // [wave][o][lane]  64 KB
  __shared__ float LIN[4][2][CC];    // lin_i per wave/query
  __shared__ float sInvT[CC], sShT[CC], sInvG[CC], sShG[CC];

  const int wid = threadIdx.x >> 6;
  const int lane = threadIdx.x & 63;
  const int q = lane >> 5;
  const int k = lane & 31;
  const int qi = blockIdx.x * 8 + wid * 2 + q;
  const int b = qi >> 12;
  const int n = qi & (NN - 1);

  // ---- precompute BN affine (block-shared, uniform over queries) ----
  if (threadIdx.x < CC) {
    const int o = threadIdx.x;
    const float inv = gT[o] / sqrtf(rvT[o] + 1e-5f);
    sInvT[o] = inv;
    sShT[o] = beT[o] - rmT[o] * inv;
  } else if (threadIdx.x < 2 * CC) {
    const int o = threadIdx.x - CC;
    const float inv = gG[o] / sqrtf(rvG[o] + 1e-5f);
    sInvG[o] = inv;
    sShG[o] = beG[o] - rmG[o] * inv;
  }

  // ---- Phase A: x_i gather + lin_i = phi(x_i) ----
  {
    const int nn = knn_nn[qi];
    const float* xi_p = ft + ((size_t)(b * MM + nn)) * CC;
    float XI[CC];
#pragma unroll
    for (int i = 0; i < CC / 4; ++i) {
      const float4 t = ((const float4*)xi_p)[i];
      XI[4 * i] = t.x; XI[4 * i + 1] = t.y; XI[4 * i + 2] = t.z; XI[4 * i + 3] = t.w;
    }
    const int o1 = k, o2 = k + 32;
    float a1 = bphi[o1], a2 = bphi[o2];
    const float* r1 = Wphi + o1 * CC;
    const float* r2 = Wphi + o2 * CC;
#pragma unroll
    for (int c = 0; c < CC; ++c) { a1 += r1[c] * XI[c]; a2 += r2[c] * XI[c]; }
    LIN[wid][q][o1] = a1;
    LIN[wid][q][o2] = a2;
  }
  __syncthreads();

  // ---- Phase B: x_j gather, pos, t1 = theta1(pos) ----
  const int kk = kidx[(size_t)qi * KK + k];
  const unsigned vbit = (kvalid[qi] >> k) & 1u;
  const float fm = (float)vbit + (1.0f - (float)qmask[qi]);

  float XJ[CC];
  {
    const float* xj_p = ft + ((size_t)(b * MM + kk)) * CC;
#pragma unroll
    for (int i = 0; i < CC / 4; ++i) {
      const float4 t = ((const float4*)xj_p)[i];
      XJ[4 * i] = t.x; XJ[4 * i + 1] = t.y; XJ[4 * i + 2] = t.z; XJ[4 * i + 3] = t.w;
    }
  }
  float T1[CC];
  {
    const float qx = qxyz[qi * 3 + 0], qy = qxyz[qi * 3 + 1], qz = qxyz[qi * 3 + 2];
    const size_t gb = ((size_t)(b * MM + kk)) * 3;
    const float p0 = (sxyz[gb + 0] - qx) * 10.0f;
    const float p1 = (sxyz[gb + 1] - qy) * 10.0f;
    const float p2 = (sxyz[gb + 2] - qz) * 10.0f;
#pragma unroll
    for (int c = 0; c < CC; ++c)
      T1[c] = b1[c] + W1[c * 3 + 0] * p0 + W1[c * 3 + 1] * p1 + W1[c * 3 + 2] * p2;
  }

  // ---- Phase C: rel = lin_i - psi(x_j) + delta,  delta = relu(bnT(theta2(t1))) ----
  for (int ot = 0; ot < 8; ++ot) {
#pragma unroll
    for (int oo = 0; oo < 8; ++oo) {
      const int o = ot * 8 + oo;
      float accP = bpsi[o];
      float accT = b2[o];
      const float* rp = Wpsi + o * CC;
      const float* rt = W2 + o * CC;
#pragma unroll
      for (int c = 0; c < CC; ++c) { accP += rp[c] * XJ[c]; accT += rt[c] * T1[c]; }
      const float delta = fmaxf(accT * sInvT[o] + sShT[o], 0.0f);
      BUF[wid][o][lane] = LIN[wid][q][o] - accP + delta;
    }
  }

  // ---- Phase D: gamma1(rel) ----
  float INr[CC];
#pragma unroll
  for (int c = 0; c < CC; ++c) INr[c] = BUF[wid][c][lane];
  for (int ot = 0; ot < 8; ++ot) {
#pragma unroll
    for (int oo = 0; oo < 8; ++oo) {
      const int o = ot * 8 + oo;
      float acc = bg1[o];
      const float* r = Wg1 + o * CC;
#pragma unroll
      for (int c = 0; c < CC; ++c) acc += r[c] * INr[c];
      BUF[wid][o][lane] = acc;
    }
  }

  // ---- Phase E: rel2 = relu(bnG(gamma2(.))) ----
#pragma unroll
  for (int c = 0; c < CC; ++c) INr[c] = BUF[wid][c][lane];
  for (int ot = 0; ot < 8; ++ot) {
#pragma unroll
    for (int oo = 0; oo < 8; ++oo) {
      const int o = ot * 8 + oo;
      float acc = bg2[o];
      const float* r = Wg2 + o * CC;
#pragma unroll
      for (int c = 0; c < CC; ++c) acc += r[c] * INr[c];
      BUF[wid][o][lane] = fmaxf(acc * sInvG[o] + sShG[o], 0.0f);
    }
  }

  // ---- Phase F: softmax over k (32 lanes of this query's half) ----
  for (int o = 0; o < CC; ++o) {
    const float v = BUF[wid][o][lane];
    float mx = v;
    mx = fmaxf(mx, __shfl_xor(mx, 1));
    mx = fmaxf(mx, __shfl_xor(mx, 2));
    mx = fmaxf(mx, __shfl_xor(mx, 4));
    mx = fmaxf(mx, __shfl_xor(mx, 8));
    mx = fmaxf(mx, __shfl_xor(mx, 16));
    const float e = __expf(v - mx);
    float s = e;
    s += __shfl_xor(s, 1);
    s += __shfl_xor(s, 2);
    s += __shfl_xor(s, 4);
    s += __shfl_xor(s, 8);
    s += __shfl_xor(s, 16);
    BUF[wid][o][lane] = e / s;
  }

  // ---- Phase G: feats = (alpha(x_j) + delta) * fmask; out = sum_k w * feats ----
  for (int ot = 0; ot < 8; ++ot) {
    float Dl[8];
#pragma unroll
    for (int oo = 0; oo < 8; ++oo) {
      const int o = ot * 8 + oo;
      float accT = b2[o];
      const float* rt = W2 + o * CC;
#pragma unroll
      for (int c = 0; c < CC; ++c) accT += rt[c] * T1[c];
      Dl[oo] = fmaxf(accT * sInvT[o] + sShT[o], 0.0f);
    }
#pragma unroll
    for (int oo = 0; oo < 8; ++oo) {
      const int o = ot * 8 + oo;
      float accA = ba[o];
      const float* ra = Wa + o * CC;
#pragma unroll
      for (int c = 0; c < CC; ++c) accA += ra[c] * XJ[c];
      const float f = (accA + Dl[oo]) * fm;
      float contrib = BUF[wid][o][lane] * f;
      contrib += __shfl_xor(contrib, 1);
      contrib += __shfl_xor(contrib, 2);
      contrib += __shfl_xor(contrib, 4);
      contrib += __shfl_xor(contrib, 8);
      contrib += __shfl_xor(contrib, 16);
      if (k == 0) out[((size_t)(b * CC + o)) * NN + n] = contrib;
    }
  }
}

// ---------------------------------------------------------------------------
extern "C" void kernel_launch(void* const* d_in, const int* in_sizes, int n_in,
                              void* d_out, int out_size, void* d_ws, size_t ws_size,
                              hipStream_t stream) {
  (void)in_sizes; (void)n_in; (void)out_size; (void)ws_size;
  const float* qxyz = (const float*)d_in[0];
  const float* sxyz = (const float*)d_in[1];
  const int* qmask = (const int*)d_in[2];
  const int* smask = (const int*)d_in[3];
  const float* sfeat = (const float*)d_in[4];
  const float* W1 = (const float*)d_in[5];
  const float* b1 = (const float*)d_in[6];
  const float* W2 = (const float*)d_in[7];
  const float* b2 = (const float*)d_in[8];
  const float* Wphi = (const float*)d_in[9];
  const float* bphi = (const float*)d_in[10];
  const float* Wpsi = (const float*)d_in[11];
  const float* bpsi = (const float*)d_in[12];
  const float* Wa = (const float*)d_in[13];
  const float* ba = (const float*)d_in[14];
  const float* Wg1 = (const float*)d_in[15];
  const float* bg1 = (const float*)d_in[16];
  const float* Wg2 = (const float*)d_in[17];
  const float* bg2 = (const float*)d_in[18];
  const float* gT = (const float*)d_in[19];
  const float* beT = (const float*)d_in[20];
  const float* rmT = (const float*)d_in[21];
  const float* rvT = (const float*)d_in[22];
  const float* gG = (const float*)d_in[23];
  const float* beG = (const float*)d_in[24];
  const float* rmG = (const float*)d_in[25];
  const float* rvG = (const float*)d_in[26];

  char* ws = (char*)d_ws;
  int* kidx = (int*)ws;                               // 16384*32*4 = 2 MB
  unsigned* kvalid = (unsigned*)(ws + 2097152);       // 64 KB
  int* knn_nn = (int*)(ws + 2097152 + 65536);         // 64 KB
  float* ft = (float*)(ws + 2097152 + 131072);        // 4 MB

  hipLaunchKernelGGL(pt_transpose_feat, dim3(64), dim3(256), 0, stream, sfeat, ft);
  hipLaunchKernelGGL(pt_knn_kernel, dim3(4096), dim3(256), 0, stream,
                     qxyz, sxyz, smask, kidx, kvalid, knn_nn);
  hipLaunchKernelGGL(pt_fused_kernel, dim3(2048), dim3(256), 0, stream,
                     qxyz, sxyz, qmask, ft, kidx, kvalid, knn_nn,
                     W1, b1, W2, b2, Wphi, bphi, Wpsi, bpsi, Wa, ba,
                     Wg1, bg1, Wg2, bg2, gT, beT, rmT, rvT, gG, beG, rmG, rvG,
                     (float*)d_out);
}